// Round 2
// baseline (272.018 us; speedup 1.0000x reference)
//
#include <hip/hip_runtime.h>
#include <math.h>

#define NB 16
#define NA 5
#define NH 96
#define NW 96
#define MAXT 50
#define NC 40
#define CH 45      // 5 + NUM_CLASSES
#define TGT_W 53   // 13 + NUM_CLASSES
#define NCELL (NH*NW)          // 9216
#define NTGT (NB*MAXT)         // 800
#define TOTF4 8294400          // NB*NA*NH*NW*CH / 4
#define IGNORE_THRES 0.5f

// anchors / SCALE
__device__ __constant__ float c_AW[5] = {1.f, 2.f, 4.f, 2.f, 4.f};
__device__ __constant__ float c_AH[5] = {1.f, 2.f, 4.f, 4.f, 2.f};

// ws layout:
//  doubles acc[10] @0 :
//   [0]=sum softplus(conf) all cells  [1]=cmf_bce corr  [2]=cmf count corr
//   [3]=mask_bce  [4]=cls ce  [5..8]=x,y,w,h sq err  [9]=nM
//  int iacc[2] @80 : [0]=nProposals [1]=worklist count
//  staging per-target (800): key,meta,fx,fy,gw,gh
//  worklist: 2 ints x 4000

__device__ __forceinline__ float softplusf(float p) {
    return fmaxf(p, 0.f) + log1pf(expf(-fabsf(p)));
}

// ---------- Kernel A: one wave per target ----------
__global__ __launch_bounds__(64) void tgt_phase1(
    const float* __restrict__ pred, const float* __restrict__ tgt,
    const int* __restrict__ tsz, double* acc, int* iacc,
    int* keyG, int* metaG, float* fxG, float* fyG, float* gwG, float* ghG) {
    const int bt = blockIdx.x;
    const int b = bt / MAXT, t = bt % MAXT;
    const int lane = threadIdx.x;

    if (bt == 0) {                     // zero accumulators (A runs first)
        if (lane < 10) acc[lane] = 0.0;
        if (lane < 2)  iacc[lane] = 0;
    }

    const bool valid = t < tsz[b];
    const float* row = tgt + (size_t)bt * TGT_W;
    const float inv_s = 0.0625f;
    float gx = row[0] * inv_s, gy = row[1] * inv_s;
    float gh_ = row[3] * inv_s, gw_ = row[4] * inv_s;
    int gi = (int)gx, gj = (int)gy;

    // label argmax across lanes (first-max)
    float lv = (lane < NC) ? row[13 + lane] : -1e30f;
    int   li = (lane < NC) ? lane : (1 << 30);
    #pragma unroll
    for (int off = 32; off; off >>= 1) {
        float ov = __shfl_xor(lv, off);
        int   oi = __shfl_xor(li, off);
        if (ov > lv || (ov == lv && oi < li)) { lv = ov; li = oi; }
    }
    int lbl = li;

    // anchor IoUs (redundant on all lanes)
    float best_iou = -1e30f; int best = 0; int ign = 0;
    #pragma unroll
    for (int a = 0; a < 5; ++a) {
        float iw = fmaxf(fminf(gw_, c_AW[a]) + 1.f, 0.f);
        float ih = fmaxf(fminf(gh_, c_AH[a]) + 1.f, 0.f);
        float inter = iw * ih;
        float iou = inter / ((gw_ + 1.f) * (gh_ + 1.f) +
                             (c_AW[a] + 1.f) * (c_AH[a] + 1.f) - inter + 1e-16f);
        if (iou > IGNORE_THRES) ign |= (1 << a);
        if (iou > best_iou) { best_iou = iou; best = a; }
    }

    // coalesced read of the 45-float pred fragment at (b,best,gj,gi)
    size_t pbase = ((((size_t)b * NA + best) * NH + gj) * NW + gi) * CH;
    float pv = (lane < CH) ? pred[pbase + lane] : -1e30f;
    float pc = __shfl(pv, 0);
    float px = __shfl(pv, 1) + (float)gi;
    float py = __shfl(pv, 2) + (float)gj;
    float ph = expf(__shfl(pv, 3)) * c_AH[best];
    float pw = expf(__shfl(pv, 4)) * c_AW[best];

    // box IoU
    float gx1 = gx - gw_ * 0.5f, gx2 = gx + gw_ * 0.5f;
    float gy1 = gy - gh_ * 0.5f, gy2 = gy + gh_ * 0.5f;
    float px1 = px - pw * 0.5f, px2 = px + pw * 0.5f;
    float py1 = py - ph * 0.5f, py2 = py + ph * 0.5f;
    float iw2 = fmaxf(fminf(gx2, px2) - fmaxf(gx1, px1) + 1.f, 0.f);
    float ih2 = fmaxf(fminf(gy2, py2) - fmaxf(gy1, py1) + 1.f, 0.f);
    float inter2 = iw2 * ih2;
    float ga = (gx2 - gx1 + 1.f) * (gy2 - gy1 + 1.f);
    float pa = (px2 - px1 + 1.f) * (py2 - py1 + 1.f);
    float iou2 = inter2 / (ga + pa - inter2 + 1e-16f);

    // pred cls argmax across lanes (first-max)
    float cv = (lane >= 5 && lane < CH) ? pv : -1e30f;
    int   ci = (lane >= 5 && lane < CH) ? (lane - 5) : (1 << 30);
    #pragma unroll
    for (int off = 32; off; off >>= 1) {
        float ov = __shfl_xor(cv, off);
        int   oi = __shfl_xor(ci, off);
        if (ov > cv || (ov == cv && oi < ci)) { cv = ov; ci = oi; }
    }
    bool correct = valid && (iou2 > 0.5f) && (ci == lbl) && (pc > 0.5f);

    if (lane == 0) {
        keyG[bt]  = valid ? (gj * NW + gi) : -1;
        metaG[bt] = best | (ign << 3) | (lbl << 8) | ((correct ? 1 : 0) << 14);
        fxG[bt] = gx - (float)gi; fyG[bt] = gy - (float)gj;
        gwG[bt] = gw_;            ghG[bt] = gh_;
    }
}

// ---------- Kernel B: ownership resolution per batch, emit worklist ----------
__global__ __launch_bounds__(64) void ownership(
    const int* __restrict__ keyG, const int* __restrict__ metaG,
    int* iacc, int* wlist) {
    __shared__ int sk[MAXT], sm[MAXT];
    const int b = blockIdx.x, t = threadIdx.x;
    if (t < MAXT) { sk[t] = keyG[b * MAXT + t]; sm[t] = metaG[b * MAXT + t]; }
    __syncthreads();
    if (t >= MAXT) return;
    const int myKey = sk[t];
    if (myKey < 0) return;
    for (int u = t + 1; u < MAXT; ++u)
        if (sk[u] == myKey) return;          // not the last writer

    int cm = 0x1F, m = 0;
    int w[5] = {-1, -1, -1, -1, -1};
    for (int u = 0; u < MAXT; ++u) {
        if (sk[u] != myKey) continue;
        int mu = sm[u];
        cm &= ~((mu >> 3) & 0x1F);           // ignore bits -> 0
        int bn = mu & 7;
        cm |= (1 << bn); m |= (1 << bn);     // best -> 1
        w[bn] = u;
    }
    int pos = atomicAdd(&iacc[1], 5);
    #pragma unroll
    for (int a = 0; a < 5; ++a) {
        int ca = (b * NA + a) * NCELL + myKey;   // < 2^20
        int flags = ca | (((m >> a) & 1) << 20) | (((cm >> a) & 1) << 21);
        wlist[2 * (pos + a)]     = flags;
        wlist[2 * (pos + a) + 1] = ((m >> a) & 1) ? (b * MAXT + w[a]) : -1;
    }
}

// ---------- Kernel C: one wave per worklist entry ----------
__global__ __launch_bounds__(1024) void corrections(
    const float* __restrict__ pred, double* acc, const int* __restrict__ iacc,
    const int* __restrict__ wlist, const int* __restrict__ metaG,
    const float* __restrict__ fxG, const float* __restrict__ fyG,
    const float* __restrict__ gwG, const float* __restrict__ ghG) {
    const int wave = threadIdx.x >> 6, lane = threadIdx.x & 63;
    const int idx = blockIdx.x * 16 + wave;
    const int count = iacc[1];
    double loc[9];
    #pragma unroll
    for (int c = 0; c < 9; ++c) loc[c] = 0.0;

    if (idx < count) {
        int flags = wlist[2 * idx], writer = wlist[2 * idx + 1];
        int ca = flags & 0xFFFFF;
        int ma = (flags >> 20) & 1, cma = (flags >> 21) & 1;
        size_t base = (size_t)ca * CH;
        float v = (lane < CH) ? pred[base + lane] : -1e30f;
        float p = __shfl(v, 0);
        float s0 = softplusf(p);
        int cmf = (cma != ma) ? 1 : 0;
        loc[0] = (cmf ? (double)(s0 - p * (float)ma) : 0.0) - (double)s0;
        loc[1] = (double)(cmf - 1);
        if (ma) {
            loc[2] = (double)(s0 - p);
            loc[8] = 1.0;
            float x = __shfl(v, 1), y = __shfl(v, 2);
            float hh = __shfl(v, 3), wv = __shfl(v, 4);
            float fx = fxG[writer], fy = fyG[writer];
            float gww = gwG[writer], ghh = ghG[writer];
            int a = (ca / NCELL) % NA;
            int lbl = (metaG[writer] >> 8) & 0x3F;
            float tw_ = logf(gww / c_AW[a] + 1e-16f);
            float th_ = logf(ghh / c_AH[a] + 1e-16f);
            loc[4] = (double)((x - fx) * (x - fx));
            loc[5] = (double)((y - fy) * (y - fy));
            loc[6] = (double)((wv - tw_) * (wv - tw_));
            loc[7] = (double)((hh - th_) * (hh - th_));
            // cls logsumexp over lanes 5..44
            float cvv = (lane >= 5 && lane < CH) ? v : -1e30f;
            float mx = cvv;
            #pragma unroll
            for (int off = 32; off; off >>= 1) mx = fmaxf(mx, __shfl_xor(mx, off));
            float e = (lane >= 5 && lane < CH) ? expf(v - mx) : 0.f;
            #pragma unroll
            for (int off = 32; off; off >>= 1) e += __shfl_xor(e, off);
            float cll = __shfl(v, 5 + lbl);
            loc[3] = (double)(logf(e) + mx - cll);
        }
    }

    __shared__ double red[16][9];
    if (lane == 0) {
        #pragma unroll
        for (int c = 0; c < 9; ++c) red[wave][c] = loc[c];
    }
    __syncthreads();
    if (threadIdx.x < 9) {
        double s = 0.0;
        #pragma unroll
        for (int wv = 0; wv < 16; ++wv) s += red[wv][threadIdx.x];
        if (s != 0.0) atomicAdd(&acc[1 + threadIdx.x], s);
    }
}

// ---------- conf pass: coalesced float4 stream over the whole tensor ----------
__global__ __launch_bounds__(256) void conf_pass2(
    const float4* __restrict__ pf, double* acc, int* iacc) {
    float bce = 0.f; int prop = 0;
    const int stride = gridDim.x * blockDim.x;
    for (int i = blockIdx.x * blockDim.x + threadIdx.x; i < TOTF4; i += stride) {
        float4 q = pf[i];
        int r = i % 45;            // conf lives at r in {0,11,22,33} -> lane j = r/11
        float cv; bool has = true;
        if (r == 0)       cv = q.x;
        else if (r == 11) cv = q.y;
        else if (r == 22) cv = q.z;
        else if (r == 33) cv = q.w;
        else has = false;
        if (has) { bce += softplusf(cv); prop += (cv > 0.f) ? 1 : 0; }
    }
    #pragma unroll
    for (int off = 32; off; off >>= 1) {
        bce  += __shfl_down(bce, off);
        prop += __shfl_down(prop, off);
    }
    __shared__ float sb[4];
    __shared__ int   sp[4];
    int wid = threadIdx.x >> 6, lane = threadIdx.x & 63;
    if (lane == 0) { sb[wid] = bce; sp[wid] = prop; }
    __syncthreads();
    if (threadIdx.x == 0) {
        atomicAdd(&acc[0], (double)(sb[0] + sb[1] + sb[2] + sb[3]));
        atomicAdd(&iacc[0], sp[0] + sp[1] + sp[2] + sp[3]);
    }
}

// ---------- finalize ----------
__global__ __launch_bounds__(256) void finalize(
    const double* __restrict__ acc, const int* __restrict__ iacc,
    const int* __restrict__ tsz, const int* __restrict__ metaG, float* out) {
    __shared__ int sred[256];
    int s = 0;
    for (int i = threadIdx.x; i < NTGT; i += 256) s += (metaG[i] >> 14) & 1;
    sred[threadIdx.x] = s;
    __syncthreads();
    for (int off = 128; off; off >>= 1) {
        if (threadIdx.x < off) sred[threadIdx.x] += sred[threadIdx.x + off];
        __syncthreads();
    }
    if (threadIdx.x != 0) return;
    int nCor = sred[0];
    int nGT = 0;
    for (int b = 0; b < NB; ++b) nGT += tsz[b];

    double nM = acc[9];
    double inv_nM = 1.0 / (nM > 0.0 ? nM : 1e-16);
    double l_coord = (acc[5] + acc[6] + acc[7] + acc[8]) * inv_nM;
    double sum_cmf = (double)(NB * NA * NH * NW) + acc[2];
    double l_conf = (acc[0] + acc[1]) / sum_cmf + acc[3] * inv_nM;
    double l_cls = (1.0 / (double)NB) * acc[4] * inv_nM;
    double loss = l_coord + l_conf + l_cls;
    int nProp = iacc[0];
    float recall = (float)nCor / (float)(nGT > 1 ? nGT : 1);
    float precision = (nProp > 0) ? ((float)nCor / fmaxf((float)nProp, 1.f)) : 1.f;
    out[0] = (float)loss;
    out[1] = (float)l_coord;
    out[2] = (float)l_conf;
    out[3] = (float)l_cls;
    out[4] = recall;
    out[5] = precision;
}

extern "C" void kernel_launch(void* const* d_in, const int* in_sizes, int n_in,
                              void* d_out, int out_size, void* d_ws, size_t ws_size,
                              hipStream_t stream) {
    const float* pred = (const float*)d_in[0];
    const float* tgt  = (const float*)d_in[1];
    const int*   tsz  = (const int*)d_in[2];
    float* out = (float*)d_out;

    double* acc = (double*)d_ws;
    int* iacc   = (int*)((char*)d_ws + 80);
    int* keyG   = (int*)((char*)d_ws + 96);
    int* metaG  = keyG + NTGT;
    float* fxG  = (float*)(metaG + NTGT);
    float* fyG  = fxG + NTGT;
    float* gwG  = fyG + NTGT;
    float* ghG  = gwG + NTGT;
    int* wlist  = (int*)(ghG + NTGT);   // 2*4000 ints

    tgt_phase1<<<NTGT, 64, 0, stream>>>(pred, tgt, tsz, acc, iacc,
                                        keyG, metaG, fxG, fyG, gwG, ghG);
    ownership<<<NB, 64, 0, stream>>>(keyG, metaG, iacc, wlist);
    corrections<<<250, 1024, 0, stream>>>(pred, acc, iacc, wlist,
                                          metaG, fxG, fyG, gwG, ghG);
    conf_pass2<<<512, 256, 0, stream>>>((const float4*)pred, acc, iacc);
    finalize<<<1, 256, 0, stream>>>(acc, iacc, tsz, metaG, out);
}

// Round 3
// 217.853 us; speedup vs baseline: 1.2486x; 1.2486x over previous
//
#include <hip/hip_runtime.h>
#include <math.h>

#define NB 16
#define NA 5
#define NH 96
#define NW 96
#define MAXT 50
#define NC 40
#define CH 45      // 5 + NUM_CLASSES
#define TGT_W 53   // 13 + NUM_CLASSES
#define NCELL (NH*NW)          // 9216
#define NTGT (NB*MAXT)         // 800
#define TOTF4 8294400          // NB*NA*NH*NW*CH / 4
#define CONF_BLOCKS 2025       // 2025*1024 threads; *4 f4/thread = TOTF4
#define CONF_STRIDE 2073600    // 2025*1024 ; % 45 == 0  (key invariant)
#define IGNORE_THRES 0.5f

// anchors / SCALE
__device__ __constant__ float c_AW[5] = {1.f, 2.f, 4.f, 2.f, 4.f};
__device__ __constant__ float c_AH[5] = {1.f, 2.f, 4.f, 4.f, 2.f};

// ws layout (bytes):
//  @0    acc[10] doubles: [0]=unused(now via partials) [1]=cmf_bce corr [2]=cmf cnt corr
//        [3]=mask_bce [4]=cls ce [5..8]=x,y,w,h sq err [9]=nM
//  @80   iacc[2] ints: [0]=unused [1]=worklist count
//  @96   keyG[800] metaG[800] fx/fy/gw/gh[800 each]
//  @19296 wlist[2*4000]
//  @51296 partial_d[2025] doubles (per-block conf bce sums)
//  @67496 partial_i[2025] ints   (per-block proposal counts)

__device__ __forceinline__ float softplusf(float p) {
    return fmaxf(p, 0.f) + log1pf(expf(-fabsf(p)));
}

__device__ __forceinline__ float pick(float4 q, int comp) {
    return comp == 0 ? q.x : comp == 1 ? q.y : comp == 2 ? q.z : q.w;
}

// ---------- Kernel A: one wave per target (also zeroes accumulators) ----------
__global__ __launch_bounds__(64) void tgt_phase1(
    const float* __restrict__ pred, const float* __restrict__ tgt,
    const int* __restrict__ tsz, double* acc, int* iacc,
    int* keyG, int* metaG, float* fxG, float* fyG, float* gwG, float* ghG) {
    const int bt = blockIdx.x;
    const int b = bt / MAXT, t = bt % MAXT;
    const int lane = threadIdx.x;

    if (bt == 0) {
        if (lane < 10) acc[lane] = 0.0;
        if (lane < 2)  iacc[lane] = 0;
    }

    const bool valid = t < tsz[b];
    const float* row = tgt + (size_t)bt * TGT_W;
    const float inv_s = 0.0625f;
    float gx = row[0] * inv_s, gy = row[1] * inv_s;
    float gh_ = row[3] * inv_s, gw_ = row[4] * inv_s;
    int gi = (int)gx, gj = (int)gy;

    // label argmax across lanes (first-max)
    float lv = (lane < NC) ? row[13 + lane] : -1e30f;
    int   li = (lane < NC) ? lane : (1 << 30);
    #pragma unroll
    for (int off = 32; off; off >>= 1) {
        float ov = __shfl_xor(lv, off);
        int   oi = __shfl_xor(li, off);
        if (ov > lv || (ov == lv && oi < li)) { lv = ov; li = oi; }
    }
    int lbl = li;

    // anchor IoUs (redundant on all lanes)
    float best_iou = -1e30f; int best = 0; int ign = 0;
    #pragma unroll
    for (int a = 0; a < 5; ++a) {
        float iw = fmaxf(fminf(gw_, c_AW[a]) + 1.f, 0.f);
        float ih = fmaxf(fminf(gh_, c_AH[a]) + 1.f, 0.f);
        float inter = iw * ih;
        float iou = inter / ((gw_ + 1.f) * (gh_ + 1.f) +
                             (c_AW[a] + 1.f) * (c_AH[a] + 1.f) - inter + 1e-16f);
        if (iou > IGNORE_THRES) ign |= (1 << a);
        if (iou > best_iou) { best_iou = iou; best = a; }
    }

    // coalesced read of the 45-float pred fragment at (b,best,gj,gi)
    size_t pbase = ((((size_t)b * NA + best) * NH + gj) * NW + gi) * CH;
    float pv = (lane < CH) ? pred[pbase + lane] : -1e30f;
    float pc = __shfl(pv, 0);
    float px = __shfl(pv, 1) + (float)gi;
    float py = __shfl(pv, 2) + (float)gj;
    float ph = expf(__shfl(pv, 3)) * c_AH[best];
    float pw = expf(__shfl(pv, 4)) * c_AW[best];

    float gx1 = gx - gw_ * 0.5f, gx2 = gx + gw_ * 0.5f;
    float gy1 = gy - gh_ * 0.5f, gy2 = gy + gh_ * 0.5f;
    float px1 = px - pw * 0.5f, px2 = px + pw * 0.5f;
    float py1 = py - ph * 0.5f, py2 = py + ph * 0.5f;
    float iw2 = fmaxf(fminf(gx2, px2) - fmaxf(gx1, px1) + 1.f, 0.f);
    float ih2 = fmaxf(fminf(gy2, py2) - fmaxf(gy1, py1) + 1.f, 0.f);
    float inter2 = iw2 * ih2;
    float ga = (gx2 - gx1 + 1.f) * (gy2 - gy1 + 1.f);
    float pa = (px2 - px1 + 1.f) * (py2 - py1 + 1.f);
    float iou2 = inter2 / (ga + pa - inter2 + 1e-16f);

    // pred cls argmax across lanes (first-max)
    float cv = (lane >= 5 && lane < CH) ? pv : -1e30f;
    int   ci = (lane >= 5 && lane < CH) ? (lane - 5) : (1 << 30);
    #pragma unroll
    for (int off = 32; off; off >>= 1) {
        float ov = __shfl_xor(cv, off);
        int   oi = __shfl_xor(ci, off);
        if (ov > cv || (ov == cv && oi < ci)) { cv = ov; ci = oi; }
    }
    bool correct = valid && (iou2 > 0.5f) && (ci == lbl) && (pc > 0.5f);

    if (lane == 0) {
        keyG[bt]  = valid ? (gj * NW + gi) : -1;
        metaG[bt] = best | (ign << 3) | (lbl << 8) | ((correct ? 1 : 0) << 14);
        fxG[bt] = gx - (float)gi; fyG[bt] = gy - (float)gj;
        gwG[bt] = gw_;            ghG[bt] = gh_;
    }
}

// ---------- Kernel B: ownership resolution per batch, emit worklist ----------
__global__ __launch_bounds__(64) void ownership(
    const int* __restrict__ keyG, const int* __restrict__ metaG,
    int* iacc, int* wlist) {
    __shared__ int sk[MAXT], sm[MAXT];
    const int b = blockIdx.x, t = threadIdx.x;
    if (t < MAXT) { sk[t] = keyG[b * MAXT + t]; sm[t] = metaG[b * MAXT + t]; }
    __syncthreads();
    if (t >= MAXT) return;
    const int myKey = sk[t];
    if (myKey < 0) return;
    for (int u = t + 1; u < MAXT; ++u)
        if (sk[u] == myKey) return;          // not the last writer

    int cm = 0x1F, m = 0;
    int w[5] = {-1, -1, -1, -1, -1};
    for (int u = 0; u < MAXT; ++u) {
        if (sk[u] != myKey) continue;
        int mu = sm[u];
        cm &= ~((mu >> 3) & 0x1F);           // ignore bits -> 0
        int bn = mu & 7;
        cm |= (1 << bn); m |= (1 << bn);     // best -> 1
        w[bn] = u;
    }
    int pos = atomicAdd(&iacc[1], 5);
    #pragma unroll
    for (int a = 0; a < 5; ++a) {
        int ca = (b * NA + a) * NCELL + myKey;   // < 2^20
        int flags = ca | (((m >> a) & 1) << 20) | (((cm >> a) & 1) << 21);
        wlist[2 * (pos + a)]     = flags;
        wlist[2 * (pos + a) + 1] = ((m >> a) & 1) ? (b * MAXT + w[a]) : -1;
    }
}

// ---------- Kernel C: one wave per worklist entry ----------
__global__ __launch_bounds__(1024) void corrections(
    const float* __restrict__ pred, double* acc, const int* __restrict__ iacc,
    const int* __restrict__ wlist, const int* __restrict__ metaG,
    const float* __restrict__ fxG, const float* __restrict__ fyG,
    const float* __restrict__ gwG, const float* __restrict__ ghG) {
    const int wave = threadIdx.x >> 6, lane = threadIdx.x & 63;
    const int idx = blockIdx.x * 16 + wave;
    const int count = iacc[1];
    double loc[9];
    #pragma unroll
    for (int c = 0; c < 9; ++c) loc[c] = 0.0;

    if (idx < count) {
        int flags = wlist[2 * idx], writer = wlist[2 * idx + 1];
        int ca = flags & 0xFFFFF;
        int ma = (flags >> 20) & 1, cma = (flags >> 21) & 1;
        size_t base = (size_t)ca * CH;
        float v = (lane < CH) ? pred[base + lane] : -1e30f;
        float p = __shfl(v, 0);
        float s0 = softplusf(p);
        int cmf = (cma != ma) ? 1 : 0;
        loc[0] = (cmf ? (double)(s0 - p * (float)ma) : 0.0) - (double)s0;
        loc[1] = (double)(cmf - 1);
        if (ma) {
            loc[2] = (double)(s0 - p);
            loc[8] = 1.0;
            float x = __shfl(v, 1), y = __shfl(v, 2);
            float hh = __shfl(v, 3), wv = __shfl(v, 4);
            float fx = fxG[writer], fy = fyG[writer];
            float gww = gwG[writer], ghh = ghG[writer];
            int a = (ca / NCELL) % NA;
            int lbl = (metaG[writer] >> 8) & 0x3F;
            float tw_ = logf(gww / c_AW[a] + 1e-16f);
            float th_ = logf(ghh / c_AH[a] + 1e-16f);
            loc[4] = (double)((x - fx) * (x - fx));
            loc[5] = (double)((y - fy) * (y - fy));
            loc[6] = (double)((wv - tw_) * (wv - tw_));
            loc[7] = (double)((hh - th_) * (hh - th_));
            // cls logsumexp over lanes 5..44
            float cvv = (lane >= 5 && lane < CH) ? v : -1e30f;
            float mx = cvv;
            #pragma unroll
            for (int off = 32; off; off >>= 1) mx = fmaxf(mx, __shfl_xor(mx, off));
            float e = (lane >= 5 && lane < CH) ? expf(v - mx) : 0.f;
            #pragma unroll
            for (int off = 32; off; off >>= 1) e += __shfl_xor(e, off);
            float cll = __shfl(v, 5 + lbl);
            loc[3] = (double)(logf(e) + mx - cll);
        }
    }

    __shared__ double red[16][9];
    if (lane == 0) {
        #pragma unroll
        for (int c = 0; c < 9; ++c) red[wave][c] = loc[c];
    }
    __syncthreads();
    if (threadIdx.x < 9) {
        double s = 0.0;
        #pragma unroll
        for (int wv = 0; wv < 16; ++wv) s += red[wv][threadIdx.x];
        if (s != 0.0) atomicAdd(&acc[1 + threadIdx.x], s);
    }
}

// ---------- conf pass: flat stream, 4 independent f4 loads/thread, no loop ----------
__global__ __launch_bounds__(1024) void conf_pass3(
    const float4* __restrict__ pf, double* partial_d, int* partial_i) {
    const int tid = blockIdx.x * 1024 + threadIdx.x;   // 0 .. CONF_STRIDE-1
    // 4 loads at stride CONF_STRIDE (≡ 0 mod 45): same channel phase for all 4
    float4 q0 = pf[tid];
    float4 q1 = pf[tid + CONF_STRIDE];
    float4 q2 = pf[tid + 2 * CONF_STRIDE];
    float4 q3 = pf[tid + 3 * CONF_STRIDE];

    float bce = 0.f; int prop = 0;
    int r = tid % 45;   // one mod per thread, total
    if (r == 0 || r == 11 || r == 22 || r == 33) {
        int comp = r / 11;
        float c0 = pick(q0, comp), c1 = pick(q1, comp);
        float c2 = pick(q2, comp), c3 = pick(q3, comp);
        bce = softplusf(c0) + softplusf(c1) + softplusf(c2) + softplusf(c3);
        prop = (c0 > 0.f) + (c1 > 0.f) + (c2 > 0.f) + (c3 > 0.f);
    }

    #pragma unroll
    for (int off = 32; off; off >>= 1) {
        bce  += __shfl_down(bce, off);
        prop += __shfl_down(prop, off);
    }
    __shared__ float sb[16];
    __shared__ int   sp[16];
    int wid = threadIdx.x >> 6, lane = threadIdx.x & 63;
    if (lane == 0) { sb[wid] = bce; sp[wid] = prop; }
    __syncthreads();
    if (threadIdx.x == 0) {
        float tb = 0.f; int tp = 0;
        #pragma unroll
        for (int w = 0; w < 16; ++w) { tb += sb[w]; tp += sp[w]; }
        partial_d[blockIdx.x] = (double)tb;
        partial_i[blockIdx.x] = tp;
    }
}

// ---------- finalize: reduce partials + compute the 6 outputs ----------
__global__ __launch_bounds__(256) void finalize(
    const double* __restrict__ acc, const int* __restrict__ iacc,
    const int* __restrict__ tsz, const int* __restrict__ metaG,
    const double* __restrict__ partial_d, const int* __restrict__ partial_i,
    float* out) {
    __shared__ double sd[256];
    __shared__ int    si[256], sc[256];
    double db = 0.0; int ip = 0, cor = 0;
    for (int i = threadIdx.x; i < CONF_BLOCKS; i += 256) { db += partial_d[i]; ip += partial_i[i]; }
    for (int i = threadIdx.x; i < NTGT; i += 256) cor += (metaG[i] >> 14) & 1;
    sd[threadIdx.x] = db; si[threadIdx.x] = ip; sc[threadIdx.x] = cor;
    __syncthreads();
    for (int off = 128; off; off >>= 1) {
        if (threadIdx.x < off) {
            sd[threadIdx.x] += sd[threadIdx.x + off];
            si[threadIdx.x] += si[threadIdx.x + off];
            sc[threadIdx.x] += sc[threadIdx.x + off];
        }
        __syncthreads();
    }
    if (threadIdx.x != 0) return;
    double sum_bce0 = sd[0];
    int nProp = si[0], nCor = sc[0];
    int nGT = 0;
    for (int b = 0; b < NB; ++b) nGT += tsz[b];

    double nM = acc[9];
    double inv_nM = 1.0 / (nM > 0.0 ? nM : 1e-16);
    double l_coord = (acc[5] + acc[6] + acc[7] + acc[8]) * inv_nM;
    double sum_cmf = (double)(NB * NA * NH * NW) + acc[2];
    double l_conf = (sum_bce0 + acc[1]) / sum_cmf + acc[3] * inv_nM;
    double l_cls = (1.0 / (double)NB) * acc[4] * inv_nM;
    double loss = l_coord + l_conf + l_cls;
    float recall = (float)nCor / (float)(nGT > 1 ? nGT : 1);
    float precision = (nProp > 0) ? ((float)nCor / fmaxf((float)nProp, 1.f)) : 1.f;
    out[0] = (float)loss;
    out[1] = (float)l_coord;
    out[2] = (float)l_conf;
    out[3] = (float)l_cls;
    out[4] = recall;
    out[5] = precision;
}

extern "C" void kernel_launch(void* const* d_in, const int* in_sizes, int n_in,
                              void* d_out, int out_size, void* d_ws, size_t ws_size,
                              hipStream_t stream) {
    const float* pred = (const float*)d_in[0];
    const float* tgt  = (const float*)d_in[1];
    const int*   tsz  = (const int*)d_in[2];
    float* out = (float*)d_out;

    double* acc = (double*)d_ws;
    int* iacc   = (int*)((char*)d_ws + 80);
    int* keyG   = (int*)((char*)d_ws + 96);
    int* metaG  = keyG + NTGT;
    float* fxG  = (float*)(metaG + NTGT);
    float* fyG  = fxG + NTGT;
    float* gwG  = fyG + NTGT;
    float* ghG  = gwG + NTGT;
    int* wlist  = (int*)(ghG + NTGT);                  // @19296, 8000 ints
    double* partial_d = (double*)((char*)d_ws + 51296); // 2025 doubles
    int*    partial_i = (int*)((char*)d_ws + 67496);    // 2025 ints

    tgt_phase1<<<NTGT, 64, 0, stream>>>(pred, tgt, tsz, acc, iacc,
                                        keyG, metaG, fxG, fyG, gwG, ghG);
    ownership<<<NB, 64, 0, stream>>>(keyG, metaG, iacc, wlist);
    corrections<<<250, 1024, 0, stream>>>(pred, acc, iacc, wlist,
                                          metaG, fxG, fyG, gwG, ghG);
    conf_pass3<<<CONF_BLOCKS, 1024, 0, stream>>>((const float4*)pred, partial_d, partial_i);
    finalize<<<1, 256, 0, stream>>>(acc, iacc, tsz, metaG, partial_d, partial_i, out);
}